// Round 2
// baseline (1714.611 us; speedup 1.0000x reference)
//
#include <hip/hip_runtime.h>
#include <math.h>

#define G_ 1000
#define N_ 256
#define E_ 1024
#define F_ 128
#define D1_ 128
#define D2_ 64
#define K1_ 32
#define K2_ 8
#define MD_ 128
#define LB_ 10
#define ME_ 16000

// ---- workspace float offsets (all 16B-aligned regions)
#define OFS_PEN   0        // float[1]
#define OFS_CNT   4        // int[1000]
#define OFS_DINVM 1004     // float[1000]
#define OFS_EMB   2004     // float[1000*512]
#define OFS_XW1M  514004   // float[1000*128]
#define OFS_HM    642004   // float[1000*128]
#define OFS_XW2M  770004   // float[1000*10]
#define OFS_LOGM  780004   // float[1000*10]
// total 790004 floats = 3.16 MB

__global__ __launch_bounds__(256)
void init_kernel(float* ws) {
  int i = blockIdx.x * 256 + threadIdx.x;
  if (i == 0) ws[OFS_PEN] = 0.f;
  if (i < 1000) ((int*)(ws + OFS_CNT))[i] = 0;
}

// One block (256 threads) per graph. thread = node.
__global__ __launch_bounds__(256, 1)
void graph_kernel(const float* __restrict__ X, const int* __restrict__ GE,
                  const float* __restrict__ W1, const float* __restrict__ b1,
                  const float* __restrict__ W2, const float* __restrict__ b2,
                  const float* __restrict__ Wf1, const float* __restrict__ bf1,
                  const float* __restrict__ Wf2, const float* __restrict__ bf2,
                  float* __restrict__ ws)
{
  extern __shared__ float smem[];
  float* A      = smem;                    // [256*36]  xw chunk staging / later att
  float* xs     = A + 256*36;              // [256*33]  x k-chunk staging
  float* h2s    = xs + 256*33;             // [256*66]  h2 (padded)
  float* enorm  = h2s + 256*66;            // [1024]
  int*   esrc   = (int*)(enorm + 1024);    // [1024]
  int*   rowst  = esrc + 1024;             // [257]
  int*   fill   = rowst + 257;             // [256]
  float* dinv_s = (float*)(fill + 256);    // [256]
  float* red    = dinv_s + 256;            // [96]

  const int g   = blockIdx.x;
  const int tid = threadIdx.x;
  const float* xg  = X + (size_t)g * (N_ * F_);
  const int*   esG = GE + (size_t)g * (2 * E_);

  // ---------------- CSR build (counting sort by dst) ----------------
  fill[tid] = 0;
  __syncthreads();
#pragma unroll
  for (int q = 0; q < 4; ++q) {
    int e = tid * 4 + q;
    atomicAdd(&fill[esG[E_ + e]], 1);
  }
  __syncthreads();
  dinv_s[tid] = rsqrtf((float)fill[tid] + 1.0f);   // +1 self loop
  if (tid == 0) {
    int s = 0;
    for (int i = 0; i < 256; ++i) { rowst[i] = s; s += fill[i]; }
    rowst[256] = s;
  }
  __syncthreads();
  fill[tid] = 0;
  __syncthreads();
#pragma unroll
  for (int q = 0; q < 4; ++q) {
    int e = tid * 4 + q;
    int sN = esG[e], dN = esG[E_ + e];
    int pos = rowst[dN] + atomicAdd(&fill[dN], 1);
    esrc[pos]  = sN;
    enorm[pos] = dinv_s[sN] * dinv_s[dN];
  }
  // barrier happens inside first kc iteration below before any esrc use

  const float dii  = dinv_s[tid] * dinv_s[tid];
  const int rbase  = rowst[tid];
  const int rcnt   = rowst[tid + 1] - rbase;

  float acc2[64];
#pragma unroll
  for (int d = 0; d < 64; ++d) acc2[d] = 0.f;

  // ---------------- conv1 (4 chunks of 32 dims) fused into conv2 accum ----------------
  for (int c = 0; c < 4; ++c) {
    float acc32[32];
#pragma unroll
    for (int j = 0; j < 32; ++j) acc32[j] = 0.f;

    for (int kc = 0; kc < 4; ++kc) {
      __syncthreads();  // previous xs readers done / scatter done (first iter)
      {
        int rr = tid >> 3, q = tid & 7;
#pragma unroll
        for (int r = 0; r < 8; ++r) {
          int i = rr + r * 32;
          float4 v = *reinterpret_cast<const float4*>(xg + i * F_ + kc * 32 + q * 4);
          float* dp = &xs[i * 33 + q * 4];
          dp[0] = v.x; dp[1] = v.y; dp[2] = v.z; dp[3] = v.w;
        }
      }
      __syncthreads();
      const float* w1p = W1 + (kc * 32) * D1_ + c * 32;
      for (int kk = 0; kk < 32; ++kk) {
        float xv = xs[tid * 33 + kk];
        const float* wr = w1p + kk * D1_;
#pragma unroll
        for (int j4 = 0; j4 < 8; ++j4) {
          float4 w = *reinterpret_cast<const float4*>(wr + j4 * 4);
          acc32[j4*4+0] += xv * w.x; acc32[j4*4+1] += xv * w.y;
          acc32[j4*4+2] += xv * w.z; acc32[j4*4+3] += xv * w.w;
        }
      }
    }
    // stage xw1 chunk to A for gather
#pragma unroll
    for (int j4 = 0; j4 < 8; ++j4) {
      float4 v; v.x = acc32[j4*4]; v.y = acc32[j4*4+1]; v.z = acc32[j4*4+2]; v.w = acc32[j4*4+3];
      *reinterpret_cast<float4*>(&A[tid * 36 + j4 * 4]) = v;
    }
    __syncthreads();
    float gacc[32];
#pragma unroll
    for (int j = 0; j < 32; ++j) gacc[j] = acc32[j] * dii;   // self loop
    for (int e = 0; e < rcnt; ++e) {
      int s = esrc[rbase + e]; float nm = enorm[rbase + e];
      const float* ap = &A[s * 36];
#pragma unroll
      for (int j4 = 0; j4 < 8; ++j4) {
        float4 w = *reinterpret_cast<const float4*>(ap + j4 * 4);
        gacc[j4*4+0] += nm * w.x; gacc[j4*4+1] += nm * w.y;
        gacc[j4*4+2] += nm * w.z; gacc[j4*4+3] += nm * w.w;
      }
    }
    __syncthreads();  // A readers done -> next chunk may overwrite
    float h1c[32];
    {
      const float* bp = b1 + c * 32;
#pragma unroll
      for (int j = 0; j < 32; ++j) h1c[j] = fmaxf(gacc[j] + bp[j], 0.f);
    }
    // conv2 partial: acc2 += h1c . W2[c*32 .. c*32+32][:]
    const float* w2p = W2 + (c * 32) * D2_;
#pragma unroll
    for (int kk = 0; kk < 32; ++kk) {
      float hv = h1c[kk];
      const float* wr = w2p + kk * D2_;
#pragma unroll
      for (int d4 = 0; d4 < 16; ++d4) {
        float4 w = *reinterpret_cast<const float4*>(wr + d4 * 4);
        acc2[d4*4+0] += hv * w.x; acc2[d4*4+1] += hv * w.y;
        acc2[d4*4+2] += hv * w.z; acc2[d4*4+3] += hv * w.w;
      }
    }
  }

  // ---------------- conv2 aggregation (2 chunks of 32) ----------------
#pragma unroll
  for (int half = 0; half < 2; ++half) {
    __syncthreads();  // previous A readers done
#pragma unroll
    for (int j4 = 0; j4 < 8; ++j4) {
      float4 v; v.x = acc2[half*32 + j4*4];   v.y = acc2[half*32 + j4*4+1];
      v.z = acc2[half*32 + j4*4+2];           v.w = acc2[half*32 + j4*4+3];
      *reinterpret_cast<float4*>(&A[tid * 36 + j4 * 4]) = v;
    }
    __syncthreads();
    float gacc[32];
#pragma unroll
    for (int j = 0; j < 32; ++j) gacc[j] = acc2[half*32 + j] * dii;
    for (int e = 0; e < rcnt; ++e) {
      int s = esrc[rbase + e]; float nm = enorm[rbase + e];
      const float* ap = &A[s * 36];
#pragma unroll
      for (int j4 = 0; j4 < 8; ++j4) {
        float4 w = *reinterpret_cast<const float4*>(ap + j4 * 4);
        gacc[j4*4+0] += nm * w.x; gacc[j4*4+1] += nm * w.y;
        gacc[j4*4+2] += nm * w.z; gacc[j4*4+3] += nm * w.w;
      }
    }
#pragma unroll
    for (int j = 0; j < 32; ++j)
      h2s[tid * 66 + half * 32 + j] = gacc[j] + b2[half * 32 + j];
  }

  // ---------------- attention: a = tanh(h2 @ Wf1 + bf1); l = a @ Wf2 + bf2 ----------------
  float a_r[32];
#pragma unroll
  for (int j = 0; j < 32; ++j) a_r[j] = bf1[j];
  for (int d = 0; d < 64; ++d) {
    float hv = h2s[tid * 66 + d];
    const float* wr = Wf1 + d * K1_;
#pragma unroll
    for (int j4 = 0; j4 < 8; ++j4) {
      float4 w = *reinterpret_cast<const float4*>(wr + j4 * 4);
      a_r[j4*4+0] += hv * w.x; a_r[j4*4+1] += hv * w.y;
      a_r[j4*4+2] += hv * w.z; a_r[j4*4+3] += hv * w.w;
    }
  }
#pragma unroll
  for (int j = 0; j < 32; ++j) a_r[j] = tanhf(a_r[j]);

  float l_r[8];
#pragma unroll
  for (int jj = 0; jj < 8; ++jj) l_r[jj] = bf2[jj];
#pragma unroll
  for (int j = 0; j < 32; ++j) {
    float av = a_r[j];
    const float* wr = Wf2 + j * K2_;
#pragma unroll
    for (int jj = 0; jj < 8; ++jj) l_r[jj] += av * wr[jj];
  }

  // ---------------- softmax over nodes (axis 0), 8 columns ----------------
  float mx[8];
#pragma unroll
  for (int jj = 0; jj < 8; ++jj) mx[jj] = l_r[jj];
#pragma unroll
  for (int off = 1; off < 64; off <<= 1) {
#pragma unroll
    for (int jj = 0; jj < 8; ++jj) mx[jj] = fmaxf(mx[jj], __shfl_xor(mx[jj], off));
  }
  int wid = tid >> 6;
  if ((tid & 63) == 0) {
#pragma unroll
    for (int jj = 0; jj < 8; ++jj) red[wid * 8 + jj] = mx[jj];
  }
  __syncthreads();
#pragma unroll
  for (int jj = 0; jj < 8; ++jj)
    mx[jj] = fmaxf(fmaxf(red[jj], red[8 + jj]), fmaxf(red[16 + jj], red[24 + jj]));
  float ex[8], sm[8];
#pragma unroll
  for (int jj = 0; jj < 8; ++jj) { ex[jj] = expf(l_r[jj] - mx[jj]); sm[jj] = ex[jj]; }
#pragma unroll
  for (int off = 1; off < 64; off <<= 1) {
#pragma unroll
    for (int jj = 0; jj < 8; ++jj) sm[jj] += __shfl_xor(sm[jj], off);
  }
  if ((tid & 63) == 0) {
#pragma unroll
    for (int jj = 0; jj < 8; ++jj) red[32 + wid * 8 + jj] = sm[jj];
  }
  __syncthreads();
  float* att_s = A;  // overlay: A free after conv2 aggregation (all threads past barrier above)
#pragma unroll
  for (int jj = 0; jj < 8; ++jj) {
    float tot = red[32 + jj] + red[40 + jj] + red[48 + jj] + red[56 + jj];
    att_s[tid * 8 + jj] = ex[jj] / tot;
  }
  __syncthreads();

  // ---------------- emb = att.T @ h2  -> global ----------------
  {
    int d = tid & 63, j0 = tid >> 6;
    float* eg = ws + OFS_EMB + (size_t)g * 512;
#pragma unroll
    for (int p = 0; p < 2; ++p) {
      int jj = j0 + p * 4;
      float acc = 0.f;
      for (int i = 0; i < 256; ++i)
        acc += att_s[i * 8 + jj] * h2s[i * 66 + d];
      eg[jj * 64 + d] = acc;
    }
  }

  // ---------------- penalty: P = att.T@att - I; sum of row L2 norms ----------------
  if (tid < 64) {
    int j = tid >> 3, k = tid & 7;
    float acc = 0.f;
    for (int i = 0; i < 256; ++i) acc += att_s[i * 8 + j] * att_s[i * 8 + k];
    if (j == k) acc -= 1.f;
    red[tid] = acc * acc;
  }
  __syncthreads();
  if (tid < 8) {
    float s2 = 0.f;
#pragma unroll
    for (int k = 0; k < 8; ++k) s2 += red[tid * 8 + k];
    red[64 + tid] = sqrtf(s2);
  }
  __syncthreads();
  if (tid == 0) {
    float p = 0.f;
#pragma unroll
    for (int k = 0; k < 8; ++k) p += red[64 + k];
    atomicAdd(&ws[OFS_PEN], p);
  }
}

// ---------------- macro level ----------------
__global__ __launch_bounds__(256)
void mcount_kernel(const int* __restrict__ me, float* ws) {
  int i = blockIdx.x * 256 + threadIdx.x;
  if (i < ME_) atomicAdd(&((int*)(ws + OFS_CNT))[me[ME_ + i]], 1);
}

__global__ __launch_bounds__(256)
void mdinv_kernel(float* ws) {
  int i = blockIdx.x * 256 + threadIdx.x;
  if (i < 1000) ws[OFS_DINVM + i] = rsqrtf((float)((int*)(ws + OFS_CNT))[i] + 1.0f);
}

__global__ __launch_bounds__(128)
void m1_kernel(const float* __restrict__ Wm1, const float* __restrict__ bm1, float* ws) {
  __shared__ float er[512];
  int g = blockIdx.x, t = threadIdx.x;
  const float* eg = ws + OFS_EMB + (size_t)g * 512;
  *reinterpret_cast<float4*>(&er[t * 4]) = *reinterpret_cast<const float4*>(&eg[t * 4]);
  __syncthreads();
  float acc = 0.f;
#pragma unroll 4
  for (int k = 0; k < 512; ++k) acc += er[k] * Wm1[k * MD_ + t];
  float dm = ws[OFS_DINVM + g];
  ws[OFS_XW1M + g * MD_ + t] = acc;
  ws[OFS_HM   + g * MD_ + t] = acc * dm * dm + bm1[t];
}

__global__ __launch_bounds__(128)
void m2_kernel(const int* __restrict__ me, float* ws) {
  int e = blockIdx.x, t = threadIdx.x;
  int s = me[e], d = me[ME_ + e];
  float nm = ws[OFS_DINVM + s] * ws[OFS_DINVM + d];
  atomicAdd(&ws[OFS_HM + d * MD_ + t], ws[OFS_XW1M + s * MD_ + t] * nm);
}

__global__ __launch_bounds__(128)
void m3_kernel(const float* __restrict__ Wm2, const float* __restrict__ bm2, float* ws) {
  __shared__ float hr[128];
  int g = blockIdx.x, t = threadIdx.x;
  hr[t] = fmaxf(ws[OFS_HM + g * MD_ + t], 0.f);
  __syncthreads();
  if (t < LB_) {
    float acc = 0.f;
#pragma unroll 4
    for (int k = 0; k < 128; ++k) acc += hr[k] * Wm2[k * LB_ + t];
    float dm = ws[OFS_DINVM + g];
    ws[OFS_XW2M + g * LB_ + t] = acc;
    ws[OFS_LOGM + g * LB_ + t] = acc * dm * dm + bm2[t];
  }
}

__global__ __launch_bounds__(256)
void m4_kernel(const int* __restrict__ me, float* ws) {
  int idx = blockIdx.x * 256 + threadIdx.x;
  if (idx < ME_ * LB_) {
    int e = idx / LB_, j = idx - e * LB_;
    int s = me[e], d = me[ME_ + e];
    float nm = ws[OFS_DINVM + s] * ws[OFS_DINVM + d];
    atomicAdd(&ws[OFS_LOGM + d * LB_ + j], ws[OFS_XW2M + s * LB_ + j] * nm);
  }
}

__global__ __launch_bounds__(64)
void m5_kernel(const float* __restrict__ ws, float* __restrict__ out) {
  int g = blockIdx.x;
  if (threadIdx.x == 0) {
    float v[10];
    float mx = -1e30f;
#pragma unroll
    for (int j = 0; j < LB_; ++j) { v[j] = ws[OFS_LOGM + g * LB_ + j]; mx = fmaxf(mx, v[j]); }
    float se = 0.f;
#pragma unroll
    for (int j = 0; j < LB_; ++j) se += expf(v[j] - mx);
    float lse = mx + logf(se);
#pragma unroll
    for (int j = 0; j < LB_; ++j) out[g * LB_ + j] = v[j] - lse;
  }
  if (g == 0 && threadIdx.x == 1) out[10000] = ws[OFS_PEN] * 0.001f;
}

extern "C" void kernel_launch(void* const* d_in, const int* in_sizes, int n_in,
                              void* d_out, int out_size, void* d_ws, size_t ws_size,
                              hipStream_t stream)
{
  const float* X   = (const float*)d_in[0];
  const int*   GE  = (const int*)d_in[1];
  const int*   MEe = (const int*)d_in[2];
  const float* W1  = (const float*)d_in[3];
  const float* b1  = (const float*)d_in[4];
  const float* W2  = (const float*)d_in[5];
  const float* b2  = (const float*)d_in[6];
  const float* Wf1 = (const float*)d_in[7];
  const float* bf1 = (const float*)d_in[8];
  const float* Wf2 = (const float*)d_in[9];
  const float* bf2 = (const float*)d_in[10];
  const float* Wm1 = (const float*)d_in[11];
  const float* bm1 = (const float*)d_in[12];
  const float* Wm2 = (const float*)d_in[13];
  const float* bm2 = (const float*)d_in[14];
  float* ws  = (float*)d_ws;
  float* out = (float*)d_out;

  init_kernel<<<5, 256, 0, stream>>>(ws);

  // LDS: 256*36 + 256*33 + 256*66 + 1024 + 1024 + 257 + 256 + 256 + 96 floats
  size_t lds = (size_t)(256*36 + 256*33 + 256*66 + 1024 + 1024 + 257 + 256 + 256 + 96) * 4;
  graph_kernel<<<G_, 256, lds, stream>>>(X, GE, W1, b1, W2, b2, Wf1, bf1, Wf2, bf2, ws);

  mcount_kernel<<<(ME_ + 255) / 256, 256, 0, stream>>>(MEe, ws);
  mdinv_kernel<<<4, 256, 0, stream>>>(ws);
  m1_kernel<<<G_, 128, 0, stream>>>(Wm1, bm1, ws);
  m2_kernel<<<ME_, 128, 0, stream>>>(MEe, ws);
  m3_kernel<<<G_, 128, 0, stream>>>(Wm2, bm2, ws);
  m4_kernel<<<(ME_ * LB_ + 255) / 256, 256, 0, stream>>>(MEe, ws);
  m5_kernel<<<G_, 64, 0, stream>>>(ws, out);
}

// Round 3
// 413.250 us; speedup vs baseline: 4.1491x; 4.1491x over previous
//
#include <hip/hip_runtime.h>
#include <math.h>

typedef __attribute__((ext_vector_type(8))) short short8;
typedef __attribute__((ext_vector_type(4))) float f32x4;

#define G_ 1000
#define N_ 256
#define E_ 1024
#define F_ 128
#define D1_ 128
#define D2_ 64
#define K1_ 32
#define K2_ 8
#define MD_ 128
#define LB_ 10
#define ME_ 16000

// ---- workspace float offsets
#define OFS_PEN   0
#define OFS_CNT   4
#define OFS_DINVM 1004
#define OFS_EMB   2004     // float[1000*512]
#define OFS_XW1M  514004
#define OFS_HM    642004
#define OFS_XW2M  770004
#define OFS_LOGM  780004
// floats end at 790004; bf16 weight-frag region starts at float index 790016
#define OFS_WFRAG 790016   // ushort: W1F[16384] then W2F[8192]

static __device__ __forceinline__ unsigned short f2bf(float f) {
  unsigned u = __builtin_bit_cast(unsigned, f);
  u += 0x7fff + ((u >> 16) & 1);          // RNE
  return (unsigned short)(u >> 16);
}
static __device__ __forceinline__ float bf2f(unsigned short h) {
  return __builtin_bit_cast(float, (unsigned)h << 16);
}

__global__ __launch_bounds__(256)
void init_kernel(float* ws) {
  int i = blockIdx.x * 256 + threadIdx.x;
  if (i == 0) ws[OFS_PEN] = 0.f;
  if (i < 1000) ((int*)(ws + OFS_CNT))[i] = 0;
}

// Pack W1 [128x128] and W2 [128x64] into bf16 MFMA B-fragment layout.
// B frag (16x16x32): lane l holds B[k = ks*32 + (l>>4)*8 + j][col = nt*16 + (l&15)], j=0..7
__global__ __launch_bounds__(256)
void prep_kernel(const float* __restrict__ W1, const float* __restrict__ W2,
                 unsigned short* __restrict__ w1f, unsigned short* __restrict__ w2f) {
  int t = blockIdx.x * 256 + threadIdx.x;
  for (int idx = t; idx < 8 * 4 * 64 * 8; idx += gridDim.x * 256) {
    int j = idx & 7, l = (idx >> 3) & 63, ks = (idx >> 9) & 3, nt = idx >> 11;
    w1f[idx] = f2bf(W1[(ks * 32 + (l >> 4) * 8 + j) * D1_ + nt * 16 + (l & 15)]);
  }
  for (int idx = t; idx < 4 * 4 * 64 * 8; idx += gridDim.x * 256) {
    int j = idx & 7, l = (idx >> 3) & 63, ks = (idx >> 9) & 3, nt = idx >> 11;
    w2f[idx] = f2bf(W2[(ks * 32 + (l >> 4) * 8 + j) * D2_ + nt * 16 + (l & 15)]);
  }
}

// One block (512 threads = 8 waves) per graph.
__global__ __launch_bounds__(512, 4)
void graph_kernel(const float* __restrict__ X, const int* __restrict__ GE,
                  const unsigned short* __restrict__ W1F, const unsigned short* __restrict__ W2F,
                  const float* __restrict__ b1, const float* __restrict__ b2,
                  const float* __restrict__ Wf1, const float* __restrict__ bf1,
                  const float* __restrict__ Wf2, const float* __restrict__ bf2,
                  float* __restrict__ ws)
{
  extern __shared__ unsigned char smemraw[];
  unsigned short* chunkA = (unsigned short*)smemraw;        // [256][40] bf16 (20480 B)
  unsigned short* h2s    = chunkA + 256 * 40;               // [256][72] bf16 (36864 B)
  float* enorm  = (float*)(h2s + 256 * 72);                 // [1024]
  int*   rowst  = (int*)(enorm + 1024);                     // [256]
  int*   fill   = rowst + 256;                              // [256]
  float* dinv_s = (float*)(fill + 256);                     // [256]
  float* red    = dinv_s + 256;                             // [96]
  unsigned short* esrc = (unsigned short*)(red + 96);       // [1024]
  float* att_s = (float*)chunkA;                            // overlay [256*8] floats
  float* wf1s  = (float*)chunkA + 2048;                     // overlay [2048] floats
  float* wf2s  = (float*)chunkA + 4096;                     // overlay [256] floats

  const int g = blockIdx.x, tid = threadIdx.x;
  const int w = tid >> 6, lane = tid & 63;
  const int l15 = lane & 15, l4 = lane >> 4;
  const float* xg = X + (size_t)g * (N_ * F_);
  const int*   esG = GE + (size_t)g * (2 * E_);

  // ---------------- CSR build ----------------
  if (tid < 256) fill[tid] = 0;
  __syncthreads();
  int s0 = esG[tid * 2], d0 = esG[E_ + tid * 2];
  int s1 = esG[tid * 2 + 1], d1 = esG[E_ + tid * 2 + 1];
  atomicAdd(&fill[d0], 1);
  atomicAdd(&fill[d1], 1);
  __syncthreads();
  int myrow = 0;
  if (tid < 256) {
    int deg = fill[tid];
    dinv_s[tid] = rsqrtf((float)deg + 1.f);
    int v = deg;
#pragma unroll
    for (int off = 1; off < 64; off <<= 1) {
      int u = __shfl_up(v, off);
      if (lane >= off) v += u;
    }
    if (lane == 63) ((int*)red)[w] = v;
    myrow = v - deg;
  }
  __syncthreads();
  if (tid < 256) {
    int pre = 0;
#pragma unroll
    for (int q = 0; q < 4; ++q) if (q < w) pre += ((int*)red)[q];
    rowst[tid] = myrow + pre;
    fill[tid] = 0;
  }
  __syncthreads();
  {
    int pos = rowst[d0] + atomicAdd(&fill[d0], 1);
    esrc[pos] = (unsigned short)s0;
    enorm[pos] = dinv_s[s0] * dinv_s[d0];
    pos = rowst[d1] + atomicAdd(&fill[d1], 1);
    esrc[pos] = (unsigned short)s1;
    enorm[pos] = dinv_s[s1] * dinv_s[d1];
  }
  __syncthreads();

  const int nd = tid >> 1, jhalf = tid & 1;
  const int rb = rowst[nd], rc = fill[nd];
  const float dii = dinv_s[nd] * dinv_s[nd];

  // ---------------- load X A-fragments (rows w*32 + mt*16 + l15) ----------------
  short8 xA[2][4];
#pragma unroll
  for (int mt = 0; mt < 2; ++mt) {
    const float* xr = xg + (w * 32 + mt * 16 + l15) * F_ + l4 * 8;
#pragma unroll
    for (int ks = 0; ks < 4; ++ks) {
      float4 u = *(const float4*)(xr + ks * 32);
      float4 v2 = *(const float4*)(xr + ks * 32 + 4);
      short8 t;
      t[0] = (short)f2bf(u.x);  t[1] = (short)f2bf(u.y);
      t[2] = (short)f2bf(u.z);  t[3] = (short)f2bf(u.w);
      t[4] = (short)f2bf(v2.x); t[5] = (short)f2bf(v2.y);
      t[6] = (short)f2bf(v2.z); t[7] = (short)f2bf(v2.w);
      xA[mt][ks] = t;
    }
  }

  f32x4 acc2[2][4];
#pragma unroll
  for (int mt = 0; mt < 2; ++mt)
#pragma unroll
    for (int nt = 0; nt < 4; ++nt) acc2[mt][nt] = (f32x4){0.f, 0.f, 0.f, 0.f};

  // ---------------- fused conv1 (MFMA) + gather + relu + conv2 (MFMA), 4 chunks ----------------
  for (int c = 0; c < 4; ++c) {
    __syncthreads();   // prior chunkA readers done
    f32x4 acc1[2][2];
#pragma unroll
    for (int mt = 0; mt < 2; ++mt) { acc1[mt][0] = (f32x4){0.f,0.f,0.f,0.f}; acc1[mt][1] = (f32x4){0.f,0.f,0.f,0.f}; }
#pragma unroll
    for (int ks = 0; ks < 4; ++ks) {
      short8 bA = *(const short8*)(W1F + (((2 * c + 0) * 4 + ks) * 64 + lane) * 8);
      short8 bB = *(const short8*)(W1F + (((2 * c + 1) * 4 + ks) * 64 + lane) * 8);
#pragma unroll
      for (int mt = 0; mt < 2; ++mt) {
        acc1[mt][0] = __builtin_amdgcn_mfma_f32_16x16x32_bf16(xA[mt][ks], bA, acc1[mt][0], 0, 0, 0);
        acc1[mt][1] = __builtin_amdgcn_mfma_f32_16x16x32_bf16(xA[mt][ks], bB, acc1[mt][1], 0, 0, 0);
      }
    }
    // write xw1 chunk to LDS (D layout: row=(l>>4)*4+r, col=l&15)
#pragma unroll
    for (int mt = 0; mt < 2; ++mt)
#pragma unroll
      for (int ntl = 0; ntl < 2; ++ntl)
#pragma unroll
        for (int r = 0; r < 4; ++r)
          chunkA[(w * 32 + mt * 16 + l4 * 4 + r) * 40 + ntl * 16 + l15] = f2bf(acc1[mt][ntl][r]);
    __syncthreads();
    // gather: node nd, 16 cols starting jhalf*16
    float gacc[16];
    {
      const unsigned short* rp = chunkA + nd * 40 + jhalf * 16;
      short8 v0 = *(const short8*)(rp);
      short8 v1 = *(const short8*)(rp + 8);
#pragma unroll
      for (int j = 0; j < 8; ++j) {
        gacc[j]     = dii * bf2f((unsigned short)v0[j]);
        gacc[8 + j] = dii * bf2f((unsigned short)v1[j]);
      }
    }
    for (int e = 0; e < rc; ++e) {
      int s = esrc[rb + e]; float nm = enorm[rb + e];
      const unsigned short* sp = chunkA + s * 40 + jhalf * 16;
      short8 v0 = *(const short8*)(sp);
      short8 v1 = *(const short8*)(sp + 8);
#pragma unroll
      for (int j = 0; j < 8; ++j) {
        gacc[j]     = fmaf(nm, bf2f((unsigned short)v0[j]), gacc[j]);
        gacc[8 + j] = fmaf(nm, bf2f((unsigned short)v1[j]), gacc[8 + j]);
      }
    }
    const float* bp = b1 + c * 32 + jhalf * 16;
    __syncthreads();   // all chunkA reads done
    {
      short8 o0, o1;
#pragma unroll
      for (int j = 0; j < 8; ++j) {
        o0[j] = (short)f2bf(fmaxf(gacc[j] + bp[j], 0.f));
        o1[j] = (short)f2bf(fmaxf(gacc[8 + j] + bp[8 + j], 0.f));
      }
      *(short8*)(chunkA + nd * 40 + jhalf * 16) = o0;
      *(short8*)(chunkA + nd * 40 + jhalf * 16 + 8) = o1;
    }
    __syncthreads();
    // conv2 partial: this chunk is k-slice c
    {
      short8 hA0 = *(const short8*)(chunkA + (w * 32 + 0 * 16 + l15) * 40 + l4 * 8);
      short8 hA1 = *(const short8*)(chunkA + (w * 32 + 1 * 16 + l15) * 40 + l4 * 8);
#pragma unroll
      for (int nt = 0; nt < 4; ++nt) {
        short8 bf = *(const short8*)(W2F + ((nt * 4 + c) * 64 + lane) * 8);
        acc2[0][nt] = __builtin_amdgcn_mfma_f32_16x16x32_bf16(hA0, bf, acc2[0][nt], 0, 0, 0);
        acc2[1][nt] = __builtin_amdgcn_mfma_f32_16x16x32_bf16(hA1, bf, acc2[1][nt], 0, 0, 0);
      }
    }
  }

  // ---------------- conv2 aggregation ----------------
#pragma unroll
  for (int mt = 0; mt < 2; ++mt)
#pragma unroll
    for (int nt = 0; nt < 4; ++nt)
#pragma unroll
      for (int r = 0; r < 4; ++r)
        h2s[(w * 32 + mt * 16 + l4 * 4 + r) * 72 + nt * 16 + l15] = f2bf(acc2[mt][nt][r]);
  __syncthreads();
  float g2[32];
  {
    const unsigned short* rp = h2s + nd * 72 + jhalf * 32;
#pragma unroll
    for (int q = 0; q < 4; ++q) {
      short8 v = *(const short8*)(rp + q * 8);
#pragma unroll
      for (int j = 0; j < 8; ++j) g2[q * 8 + j] = dii * bf2f((unsigned short)v[j]);
    }
  }
  for (int e = 0; e < rc; ++e) {
    int s = esrc[rb + e]; float nm = enorm[rb + e];
    const unsigned short* sp = h2s + s * 72 + jhalf * 32;
#pragma unroll
    for (int q = 0; q < 4; ++q) {
      short8 v = *(const short8*)(sp + q * 8);
#pragma unroll
      for (int j = 0; j < 8; ++j) g2[q * 8 + j] = fmaf(nm, bf2f((unsigned short)v[j]), g2[q * 8 + j]);
    }
  }
  const float* b2p = b2 + jhalf * 32;
  __syncthreads();   // reads done
  {
#pragma unroll
    for (int q = 0; q < 4; ++q) {
      short8 o;
#pragma unroll
      for (int j = 0; j < 8; ++j) o[j] = (short)f2bf(g2[q * 8 + j] + b2p[q * 8 + j]);
      *(short8*)(h2s + nd * 72 + jhalf * 32 + q * 8) = o;
    }
  }
  // stage Wf1/Wf2 into LDS (chunkA overlay, past att_s region)
  for (int i = tid; i < 2048; i += 512) wf1s[i] = Wf1[i];
  if (tid < 256) wf2s[tid] = Wf2[tid];
  __syncthreads();

  // ---------------- attention ----------------
  float l_r[8], ex8[8];
  if (tid < 256) {
    float a_r[32];
#pragma unroll
    for (int j = 0; j < 32; ++j) a_r[j] = bf1[j];
    const unsigned short* hrow = h2s + tid * 72;
    for (int d = 0; d < 64; d += 8) {
      short8 hv8 = *(const short8*)(hrow + d);
#pragma unroll
      for (int dj = 0; dj < 8; ++dj) {
        float hv = bf2f((unsigned short)hv8[dj]);
        const float* wr = wf1s + (d + dj) * K1_;
#pragma unroll
        for (int j4 = 0; j4 < 8; ++j4) {
          float4 wv = *(const float4*)(wr + j4 * 4);
          a_r[j4 * 4 + 0] = fmaf(hv, wv.x, a_r[j4 * 4 + 0]);
          a_r[j4 * 4 + 1] = fmaf(hv, wv.y, a_r[j4 * 4 + 1]);
          a_r[j4 * 4 + 2] = fmaf(hv, wv.z, a_r[j4 * 4 + 2]);
          a_r[j4 * 4 + 3] = fmaf(hv, wv.w, a_r[j4 * 4 + 3]);
        }
      }
    }
#pragma unroll
    for (int j = 0; j < 32; ++j) a_r[j] = tanhf(a_r[j]);
#pragma unroll
    for (int jj = 0; jj < 8; ++jj) l_r[jj] = bf2[jj];
#pragma unroll
    for (int j = 0; j < 32; ++j) {
      float av = a_r[j];
      const float* wr = wf2s + j * K2_;
#pragma unroll
      for (int jj = 0; jj < 8; ++jj) l_r[jj] = fmaf(av, wr[jj], l_r[jj]);
    }
    float mx[8];
#pragma unroll
    for (int jj = 0; jj < 8; ++jj) mx[jj] = l_r[jj];
#pragma unroll
    for (int off = 1; off < 64; off <<= 1)
#pragma unroll
      for (int jj = 0; jj < 8; ++jj) mx[jj] = fmaxf(mx[jj], __shfl_xor(mx[jj], off));
    if (lane == 0)
#pragma unroll
      for (int jj = 0; jj < 8; ++jj) red[w * 8 + jj] = mx[jj];
  }
  __syncthreads();
  if (tid < 256) {
#pragma unroll
    for (int jj = 0; jj < 8; ++jj) {
      float m = fmaxf(fmaxf(red[jj], red[8 + jj]), fmaxf(red[16 + jj], red[24 + jj]));
      ex8[jj] = expf(l_r[jj] - m);
    }
    float sm[8];
#pragma unroll
    for (int jj = 0; jj < 8; ++jj) sm[jj] = ex8[jj];
#pragma unroll
    for (int off = 1; off < 64; off <<= 1)
#pragma unroll
      for (int jj = 0; jj < 8; ++jj) sm[jj] += __shfl_xor(sm[jj], off);
    if (lane == 0)
#pragma unroll
      for (int jj = 0; jj < 8; ++jj) red[32 + w * 8 + jj] = sm[jj];
  }
  __syncthreads();
  if (tid < 256) {
#pragma unroll
    for (int jj = 0; jj < 8; ++jj) {
      float tot = red[32 + jj] + red[40 + jj] + red[48 + jj] + red[56 + jj];
      att_s[tid * 8 + jj] = ex8[jj] / tot;
    }
  }
  __syncthreads();

  // ---------------- emb = att.T @ h2 (one output per thread) ----------------
  {
    int jj = tid >> 6, d = tid & 63;
    float acc = 0.f;
    for (int i = 0; i < 256; ++i)
      acc = fmaf(att_s[i * 8 + jj], bf2f(h2s[i * 72 + d]), acc);
    ws[OFS_EMB + (size_t)g * 512 + jj * 64 + d] = acc;
  }

  // ---------------- penalty ----------------
  if (tid < 64) {
    int j = tid >> 3, k = tid & 7;
    float acc = 0.f;
    for (int i = 0; i < 256; ++i) acc += att_s[i * 8 + j] * att_s[i * 8 + k];
    if (j == k) acc -= 1.f;
    red[tid] = acc * acc;
  }
  __syncthreads();
  if (tid < 8) {
    float s2 = 0.f;
#pragma unroll
    for (int k = 0; k < 8; ++k) s2 += red[tid * 8 + k];
    red[64 + tid] = sqrtf(s2);
  }
  __syncthreads();
  if (tid == 0) {
    float p = 0.f;
#pragma unroll
    for (int k = 0; k < 8; ++k) p += red[64 + k];
    atomicAdd(&ws[OFS_PEN], p);
  }
}

// ---------------- macro level (unchanged) ----------------
__global__ __launch_bounds__(256)
void mcount_kernel(const int* __restrict__ me, float* ws) {
  int i = blockIdx.x * 256 + threadIdx.x;
  if (i < ME_) atomicAdd(&((int*)(ws + OFS_CNT))[me[ME_ + i]], 1);
}

__global__ __launch_bounds__(256)
void mdinv_kernel(float* ws) {
  int i = blockIdx.x * 256 + threadIdx.x;
  if (i < 1000) ws[OFS_DINVM + i] = rsqrtf((float)((int*)(ws + OFS_CNT))[i] + 1.0f);
}

__global__ __launch_bounds__(128)
void m1_kernel(const float* __restrict__ Wm1, const float* __restrict__ bm1, float* ws) {
  __shared__ float er[512];
  int g = blockIdx.x, t = threadIdx.x;
  const float* eg = ws + OFS_EMB + (size_t)g * 512;
  *reinterpret_cast<float4*>(&er[t * 4]) = *reinterpret_cast<const float4*>(&eg[t * 4]);
  __syncthreads();
  float acc = 0.f;
#pragma unroll 4
  for (int k = 0; k < 512; ++k) acc += er[k] * Wm1[k * MD_ + t];
  float dm = ws[OFS_DINVM + g];
  ws[OFS_XW1M + g * MD_ + t] = acc;
  ws[OFS_HM   + g * MD_ + t] = acc * dm * dm + bm1[t];
}

__global__ __launch_bounds__(128)
void m2_kernel(const int* __restrict__ me, float* ws) {
  int e = blockIdx.x, t = threadIdx.x;
  int s = me[e], d = me[ME_ + e];
  float nm = ws[OFS_DINVM + s] * ws[OFS_DINVM + d];
  atomicAdd(&ws[OFS_HM + d * MD_ + t], ws[OFS_XW1M + s * MD_ + t] * nm);
}

__global__ __launch_bounds__(128)
void m3_kernel(const float* __restrict__ Wm2, const float* __restrict__ bm2, float* ws) {
  __shared__ float hr[128];
  int g = blockIdx.x, t = threadIdx.x;
  hr[t] = fmaxf(ws[OFS_HM + g * MD_ + t], 0.f);
  __syncthreads();
  if (t < LB_) {
    float acc = 0.f;
#pragma unroll 4
    for (int k = 0; k < 128; ++k) acc += hr[k] * Wm2[k * LB_ + t];
    float dm = ws[OFS_DINVM + g];
    ws[OFS_XW2M + g * LB_ + t] = acc;
    ws[OFS_LOGM + g * LB_ + t] = acc * dm * dm + bm2[t];
  }
}

__global__ __launch_bounds__(256)
void m4_kernel(const int* __restrict__ me, float* ws) {
  int idx = blockIdx.x * 256 + threadIdx.x;
  if (idx < ME_ * LB_) {
    int e = idx / LB_, j = idx - e * LB_;
    int s = me[e], d = me[ME_ + e];
    float nm = ws[OFS_DINVM + s] * ws[OFS_DINVM + d];
    atomicAdd(&ws[OFS_LOGM + d * LB_ + j], ws[OFS_XW2M + s * LB_ + j] * nm);
  }
}

__global__ __launch_bounds__(64)
void m5_kernel(const float* __restrict__ ws, float* __restrict__ out) {
  int g = blockIdx.x;
  if (threadIdx.x == 0) {
    float v[10];
    float mx = -1e30f;
#pragma unroll
    for (int j = 0; j < LB_; ++j) { v[j] = ws[OFS_LOGM + g * LB_ + j]; mx = fmaxf(mx, v[j]); }
    float se = 0.f;
#pragma unroll
    for (int j = 0; j < LB_; ++j) se += expf(v[j] - mx);
    float lse = mx + logf(se);
#pragma unroll
    for (int j = 0; j < LB_; ++j) out[g * LB_ + j] = v[j] - lse;
  }
  if (g == 0 && threadIdx.x == 1) out[10000] = ws[OFS_PEN] * 0.001f;
}

extern "C" void kernel_launch(void* const* d_in, const int* in_sizes, int n_in,
                              void* d_out, int out_size, void* d_ws, size_t ws_size,
                              hipStream_t stream)
{
  const float* X   = (const float*)d_in[0];
  const int*   GE  = (const int*)d_in[1];
  const int*   MEe = (const int*)d_in[2];
  const float* W1  = (const float*)d_in[3];
  const float* b1  = (const float*)d_in[4];
  const float* W2  = (const float*)d_in[5];
  const float* b2  = (const float*)d_in[6];
  const float* Wf1 = (const float*)d_in[7];
  const float* bf1 = (const float*)d_in[8];
  const float* Wf2 = (const float*)d_in[9];
  const float* bf2 = (const float*)d_in[10];
  const float* Wm1 = (const float*)d_in[11];
  const float* bm1 = (const float*)d_in[12];
  const float* Wm2 = (const float*)d_in[13];
  const float* bm2 = (const float*)d_in[14];
  float* ws  = (float*)d_ws;
  float* out = (float*)d_out;

  unsigned short* w1f = (unsigned short*)(ws + OFS_WFRAG);
  unsigned short* w2f = w1f + 16384;

  prep_kernel<<<32, 256, 0, stream>>>(W1, W2, w1f, w2f);
  init_kernel<<<5, 256, 0, stream>>>(ws);

  // LDS: 20480 + 36864 + 4096 + 1024 + 1024 + 1024 + 384 + 2048 = 66944 B
  size_t lds = 66944;
  graph_kernel<<<G_, 512, lds, stream>>>(X, GE, w1f, w2f, b1, b2, Wf1, bf1, Wf2, bf2, ws);

  mcount_kernel<<<(ME_ + 255) / 256, 256, 0, stream>>>(MEe, ws);
  mdinv_kernel<<<4, 256, 0, stream>>>(ws);
  m1_kernel<<<G_, 128, 0, stream>>>(Wm1, bm1, ws);
  m2_kernel<<<ME_, 128, 0, stream>>>(MEe, ws);
  m3_kernel<<<G_, 128, 0, stream>>>(Wm2, bm2, ws);
  m4_kernel<<<(ME_ * LB_ + 255) / 256, 256, 0, stream>>>(MEe, ws);
  m5_kernel<<<G_, 64, 0, stream>>>(ws, out);
}